// Round 9
// baseline (112.103 us; speedup 1.0000x reference)
//
#include <hip/hip_runtime.h>
#include <hip/hip_bf16.h>

#define NORM_EPS 1e-12f
#define D 60
#define RP 64     // padded row length (elements) -> 128 B rows, line-aligned
#define L 24
#define SSTR 28   // per-list dwords in blob (24 sids + invc + 3 pad)
#define ITEM_STRIDE 768   // per-item blob bytes (6 cache lines)
#define BIAS_OFF 336
#define ROWS_OFF 384

__device__ __forceinline__ float wave_sum(float v) {
    #pragma unroll
    for (int off = 32; off >= 1; off >>= 1)
        v += __shfl_xor(v, off, 64);
    return v;
}

__device__ __forceinline__ int rfl(int x) { return __builtin_amdgcn_readfirstlane(x); }

__device__ __forceinline__ float bf2f(unsigned short u) {
    unsigned x = (unsigned)u << 16;
    float f;
    __builtin_memcpy(&f, &x, 4);
    return f;
}

__device__ __forceinline__ unsigned pack_bf16(float a, float b) {
    __hip_bfloat16 lo = __float2bfloat16(a);   // RNE
    __hip_bfloat16 hi = __float2bfloat16(b);
    unsigned short ul, uh;
    __builtin_memcpy(&ul, &lo, 2);
    __builtin_memcpy(&uh, &hi, 2);
    return (unsigned)ul | ((unsigned)uh << 16);
}

// ---------- precompute: L2-normalized bf16 word table (+ zero row at N) ----------
__global__ __launch_bounds__(256) void norm_bf16_tab_kernel(
    const float* __restrict__ emb, __hip_bfloat16* __restrict__ outw, int N)
{
    int row = (int)(blockIdx.x * blockDim.x + threadIdx.x);
    if (row > N) return;

    uint4* dst = (uint4*)(outw + (size_t)row * RP);
    if (row == N) {  // zero row
        uint4 z = make_uint4(0u, 0u, 0u, 0u);
        #pragma unroll
        for (int j = 0; j < 8; ++j) dst[j] = z;
        return;
    }

    const float4* src = (const float4*)(emb + (size_t)row * D);
    float4 v[15];
    #pragma unroll
    for (int i = 0; i < 15; ++i) v[i] = src[i];

    float ss = 0.f;
    #pragma unroll
    for (int i = 0; i < 15; ++i)
        ss += v[i].x * v[i].x + v[i].y * v[i].y + v[i].z * v[i].z + v[i].w * v[i].w;
    float inv = 1.f / fmaxf(sqrtf(ss), NORM_EPS);

    float f[60];
    #pragma unroll
    for (int i = 0; i < 15; ++i) {
        f[4*i+0] = v[i].x * inv; f[4*i+1] = v[i].y * inv;
        f[4*i+2] = v[i].z * inv; f[4*i+3] = v[i].w * inv;
    }
    unsigned w[32];
    #pragma unroll
    for (int i = 0; i < 30; ++i) w[i] = pack_bf16(f[2*i], f[2*i+1]);
    w[30] = 0u; w[31] = 0u;

    #pragma unroll
    for (int j = 0; j < 8; ++j)
        dst[j] = make_uint4(w[4*j+0], w[4*j+1], w[4*j+2], w[4*j+3]);
}

// ---------- sanitize: lists + invc + bias (thread-per-item, no row traffic) ----------
__global__ __launch_bounds__(256) void sanitize_kernel(
    const float* __restrict__ e_bias, const float* __restrict__ r_bias,
    const int* __restrict__ head, const int* __restrict__ relation,
    const int* __restrict__ tail,
    const int* __restrict__ hw, const int* __restrict__ rw, const int* __restrict__ tw,
    const int* __restrict__ hm, const int* __restrict__ rm, const int* __restrict__ tm,
    char* __restrict__ blob, int B, int NW)
{
    int b = (int)(blockIdx.x * blockDim.x + threadIdx.x);
    if (b >= B) return;

    char* ob = blob + (size_t)b * ITEM_STRIDE;

    const int* idp[3] = { hw, rw, tw };
    const int* mkp[3] = { hm, rm, tm };
    int* o = (int*)ob;
    #pragma unroll
    for (int s = 0; s < 3; ++s) {
        const int4* ip = (const int4*)(idp[s] + (size_t)b * L);
        const int4* mp = (const int4*)(mkp[s] + (size_t)b * L);
        int cnt = 0;
        int4* ov = (int4*)o;
        #pragma unroll
        for (int i = 0; i < L / 4; ++i) {
            int4 ti = ip[i];
            int4 tm4 = mp[i];
            int4 so;
            so.x = tm4.x ? ti.x : NW; cnt += (tm4.x ? 1 : 0);
            so.y = tm4.y ? ti.y : NW; cnt += (tm4.y ? 1 : 0);
            so.z = tm4.z ? ti.z : NW; cnt += (tm4.z ? 1 : 0);
            so.w = tm4.w ? ti.w : NW; cnt += (tm4.w ? 1 : 0);
            ov[i] = so;
        }
        float invc = 1.f / (float)(cnt > 0 ? cnt : 1);
        ov[6] = make_int4(__float_as_int(invc), 0, 0, 0);
        o += SSTR;
    }

    int h = head[b];
    int r = relation[b];
    int t = tail[b];
    *(float*)(ob + BIAS_OFF) = e_bias[h] + e_bias[t] + r_bias[r];
}

// ---------- rows: wave-per-(item,row); coalesced read, shfl-reduce, bf16 write ----------
__global__ __launch_bounds__(256) void rows_kernel(
    const float* __restrict__ ent_emb, const float* __restrict__ rel_emb,
    const int* __restrict__ head, const int* __restrict__ relation,
    const int* __restrict__ tail,
    char* __restrict__ blob, int B)
{
    unsigned rid = (unsigned)((blockIdx.x * (unsigned)blockDim.x + threadIdx.x) >> 6);
    int lane = (int)(threadIdx.x & 63u);
    unsigned nrows = 3u * (unsigned)B;
    if (rid >= nrows) return;

    unsigned b = rid / 3u;          // wave-uniform
    unsigned s = rid - 3u * b;      // 0=head, 1=rel, 2=tail

    int idx;
    const float* src;
    if (s == 0)      { idx = head[b];     src = ent_emb; }
    else if (s == 1) { idx = relation[b]; src = rel_emb; }
    else             { idx = tail[b];     src = ent_emb; }

    float v = (lane < D) ? src[(size_t)idx * D + lane] : 0.f;
    float ss = wave_sum(v * v);
    float inv = 1.f / fmaxf(sqrtf(ss), NORM_EPS);

    __hip_bfloat16 h16 = __float2bfloat16(v * inv);
    unsigned short u;
    __builtin_memcpy(&u, &h16, 2);
    if (lane >= D) u = 0;

    *(unsigned short*)(blob + (size_t)b * ITEM_STRIDE + ROWS_OFF
                       + (size_t)s * 128 + (size_t)lane * 2) = u;
}

// ---------- score: flat-issue 72 word gathers + 6-line uniform blob ----------
__global__ __launch_bounds__(256) void score_kernel_v8(
    const __hip_bfloat16* __restrict__ wt,
    const char* __restrict__ blob,
    float* __restrict__ out,
    int B)
{
    int wid = (int)((blockIdx.x * (unsigned)blockDim.x + threadIdx.x) >> 6);
    int lane = (int)(threadIdx.x & 63u);
    if (wid >= B) return;
    int b = rfl(wid);

    int d = lane;
    unsigned doff2 = (unsigned)(((d < D) ? d : 0) * 2);

    const char* ob = blob + (size_t)b * ITEM_STRIDE;
    const char* wtb = (const char*)wt;

    const int4* sb = (const int4*)ob;
    int4 q[21];
    #pragma unroll
    for (int i = 0; i < 21; ++i) q[i] = sb[i];

    unsigned off[72];
    #pragma unroll
    for (int s = 0; s < 3; ++s) {
        #pragma unroll
        for (int i = 0; i < 6; ++i) {
            int4 ti = q[s * 7 + i];
            int base = s * 24 + 4 * i;
            off[base + 0] = ((unsigned)ti.x << 7) + doff2;
            off[base + 1] = ((unsigned)ti.y << 7) + doff2;
            off[base + 2] = ((unsigned)ti.z << 7) + doff2;
            off[base + 3] = ((unsigned)ti.w << 7) + doff2;
        }
    }

    unsigned short raw[72];
    #pragma unroll
    for (int j = 0; j < 72; ++j)
        raw[j] = *(const unsigned short*)(wtb + off[j]);
    unsigned short rawh = *(const unsigned short*)(ob + ROWS_OFF + doff2);
    unsigned short rawr = *(const unsigned short*)(ob + ROWS_OFF + 128 + doff2);
    unsigned short rawt = *(const unsigned short*)(ob + ROWS_OFF + 256 + doff2);
    float bias = *(const float*)(ob + BIAS_OFF);

    float pool[3];
    #pragma unroll
    for (int s = 0; s < 3; ++s) {
        float s0 = 0.f, s1 = 0.f, s2 = 0.f, s3 = 0.f;
        #pragma unroll
        for (int l = 0; l < L; l += 4) {
            s0 += bf2f(raw[s * 24 + l + 0]);
            s1 += bf2f(raw[s * 24 + l + 1]);
            s2 += bf2f(raw[s * 24 + l + 2]);
            s3 += bf2f(raw[s * 24 + l + 3]);
        }
        float acc = (s0 + s1) + (s2 + s3);
        pool[s] = acc * __int_as_float(q[s * 7 + 6].x);
    }

    float vh = bf2f(rawh);
    float vr = bf2f(rawr);
    float vt = bf2f(rawt);

    float comb = (vh + pool[0]) + (vr + pool[1]) - (vt + pool[2]);
    comb = (d < D) ? comb : 0.f;
    float nsc = sqrtf(wave_sum(comb * comb));

    float score = -nsc + bias;
    if (lane == 0) out[wid] = score;
}

// ---------- slow fallback (round-0 verified) ----------
__device__ __forceinline__ float word_pool_slow(const float* __restrict__ word_emb,
                                                const int* __restrict__ ids,
                                                const int* __restrict__ mask,
                                                int b, int d, bool act)
{
    float acc = 0.f;
    int cnt = 0;
    #pragma unroll
    for (int l = 0; l < L; ++l) {
        int m = mask[b * L + l];
        if (m) {
            int id = ids[b * L + l];
            float v = act ? word_emb[(size_t)id * D + d] : 0.f;
            float n = sqrtf(wave_sum(v * v));
            acc += v / fmaxf(n, NORM_EPS);
            cnt += 1;
        }
    }
    return acc / (float)(cnt > 0 ? cnt : 1);
}

__global__ __launch_bounds__(256) void transe_score_slow_kernel(
    const float* __restrict__ ent_emb, const float* __restrict__ rel_emb,
    const float* __restrict__ word_emb, const float* __restrict__ e_bias,
    const float* __restrict__ r_bias,
    const int* __restrict__ head, const int* __restrict__ relation,
    const int* __restrict__ tail,
    const int* __restrict__ head_w, const int* __restrict__ rel_w,
    const int* __restrict__ tail_w,
    const int* __restrict__ head_m, const int* __restrict__ rel_m,
    const int* __restrict__ tail_m,
    float* __restrict__ out, int B)
{
    int wid = (int)((blockIdx.x * (unsigned)blockDim.x + threadIdx.x) >> 6);
    int lane = (int)(threadIdx.x & 63u);
    if (wid >= B) return;
    int d = lane;
    bool act = d < D;

    int h = head[wid], r = relation[wid], t = tail[wid];

    float vh = act ? ent_emb[(size_t)h * D + d] : 0.f;
    float vr = act ? rel_emb[(size_t)r * D + d] : 0.f;
    float vt = act ? ent_emb[(size_t)t * D + d] : 0.f;
    vh /= fmaxf(sqrtf(wave_sum(vh * vh)), NORM_EPS);
    vr /= fmaxf(sqrtf(wave_sum(vr * vr)), NORM_EPS);
    vt /= fmaxf(sqrtf(wave_sum(vt * vt)), NORM_EPS);

    float ph = word_pool_slow(word_emb, head_w, head_m, wid, d, act);
    float pr = word_pool_slow(word_emb, rel_w,  rel_m,  wid, d, act);
    float pt = word_pool_slow(word_emb, tail_w, tail_m, wid, d, act);

    float comb = (vh + ph) + (vr + pr) - (vt + pt);
    float nsc = sqrtf(wave_sum(comb * comb));
    float score = -nsc + e_bias[h] + e_bias[t] + r_bias[r];
    if (lane == 0) out[wid] = score;
}

extern "C" void kernel_launch(void* const* d_in, const int* in_sizes, int n_in,
                              void* d_out, int out_size, void* d_ws, size_t ws_size,
                              hipStream_t stream) {
    const float* ent_emb  = (const float*)d_in[0];
    const float* rel_emb  = (const float*)d_in[1];
    const float* word_emb = (const float*)d_in[2];
    const float* e_bias   = (const float*)d_in[3];
    const float* r_bias   = (const float*)d_in[4];
    const int*   head     = (const int*)d_in[5];
    const int*   relation = (const int*)d_in[6];
    const int*   tail     = (const int*)d_in[7];
    const int*   head_w   = (const int*)d_in[8];
    const int*   rel_w    = (const int*)d_in[9];
    const int*   tail_w   = (const int*)d_in[10];
    const int*   head_m   = (const int*)d_in[11];
    const int*   rel_m    = (const int*)d_in[12];
    const int*   tail_m   = (const int*)d_in[13];
    float* out = (float*)d_out;

    int B  = in_sizes[5];
    int NW = in_sizes[2] / D;   // 100000

    int wpb = 256 / 64;  // waves per block (64-lane-wave kernels)

    size_t wt_bytes   = (size_t)(NW + 1) * RP * sizeof(__hip_bfloat16);  // ~12.8 MB
    size_t blob_bytes = (size_t)B * ITEM_STRIDE;                         // ~50 MB
    size_t need = wt_bytes + blob_bytes;

    if (ws_size >= need) {
        __hip_bfloat16* wt = (__hip_bfloat16*)d_ws;
        char* blob = (char*)d_ws + wt_bytes;

        norm_bf16_tab_kernel<<<(NW + 1 + 255) / 256, 256, 0, stream>>>(word_emb, wt, NW);
        sanitize_kernel<<<(B + 255) / 256, 256, 0, stream>>>(
            e_bias, r_bias, head, relation, tail,
            head_w, rel_w, tail_w, head_m, rel_m, tail_m,
            blob, B, NW);
        unsigned nrows = 3u * (unsigned)B;
        rows_kernel<<<(nrows + wpb - 1) / wpb, 256, 0, stream>>>(
            ent_emb, rel_emb, head, relation, tail, blob, B);

        score_kernel_v8<<<(B + wpb - 1) / wpb, 256, 0, stream>>>(
            wt, blob, out, B);
    } else {
        transe_score_slow_kernel<<<(B + wpb - 1) / wpb, 256, 0, stream>>>(
            ent_emb, rel_emb, word_emb, e_bias, r_bias,
            head, relation, tail,
            head_w, rel_w, tail_w, head_m, rel_m, tail_m, out, B);
    }
}

// Round 10
// 85.601 us; speedup vs baseline: 1.3096x; 1.3096x over previous
//
#include <hip/hip_runtime.h>
#include <hip/hip_bf16.h>

#define NORM_EPS 1e-12f
#define D 60
#define RP 64     // padded word-row length (elements) -> 128 B rows, line-aligned
#define L 24

__device__ __forceinline__ float wave_sum(float v) {
    #pragma unroll
    for (int off = 32; off >= 1; off >>= 1)
        v += __shfl_xor(v, off, 64);
    return v;
}

__device__ __forceinline__ int rfl(int x) { return __builtin_amdgcn_readfirstlane(x); }

__device__ __forceinline__ float bf2f(unsigned short u) {
    unsigned x = (unsigned)u << 16;
    float f;
    __builtin_memcpy(&f, &x, 4);
    return f;
}

__device__ __forceinline__ unsigned pack_bf16(float a, float b) {
    __hip_bfloat16 lo = __float2bfloat16(a);   // RNE
    __hip_bfloat16 hi = __float2bfloat16(b);
    unsigned short ul, uh;
    __builtin_memcpy(&ul, &lo, 2);
    __builtin_memcpy(&uh, &hi, 2);
    return (unsigned)ul | ((unsigned)uh << 16);
}

// ---------- precompute: L2-normalized bf16 word table (+ zero row at N) ----------
__global__ __launch_bounds__(256) void norm_bf16_tab_kernel(
    const float* __restrict__ emb, __hip_bfloat16* __restrict__ outw, int N)
{
    int row = (int)(blockIdx.x * blockDim.x + threadIdx.x);
    if (row > N) return;

    uint4* dst = (uint4*)(outw + (size_t)row * RP);
    if (row == N) {  // zero row: masked slots gather here
        uint4 z = make_uint4(0u, 0u, 0u, 0u);
        #pragma unroll
        for (int j = 0; j < 8; ++j) dst[j] = z;
        return;
    }

    const float4* src = (const float4*)(emb + (size_t)row * D);
    float4 v[15];
    #pragma unroll
    for (int i = 0; i < 15; ++i) v[i] = src[i];

    float ss = 0.f;
    #pragma unroll
    for (int i = 0; i < 15; ++i)
        ss += v[i].x * v[i].x + v[i].y * v[i].y + v[i].z * v[i].z + v[i].w * v[i].w;
    float inv = 1.f / fmaxf(sqrtf(ss), NORM_EPS);

    float f[60];
    #pragma unroll
    for (int i = 0; i < 15; ++i) {
        f[4*i+0] = v[i].x * inv; f[4*i+1] = v[i].y * inv;
        f[4*i+2] = v[i].z * inv; f[4*i+3] = v[i].w * inv;
    }
    unsigned w[32];
    #pragma unroll
    for (int i = 0; i < 30; ++i) w[i] = pack_bf16(f[2*i], f[2*i+1]);
    w[30] = 0u; w[31] = 0u;

    #pragma unroll
    for (int j = 0; j < 8; ++j)
        dst[j] = make_uint4(w[4*j+0], w[4*j+1], w[4*j+2], w[4*j+3]);
}

// ---------- fused score: sanitize (scalar pipe) + entity norms + 72 gathers ----------
__global__ __launch_bounds__(256) void score_fused_kernel(
    const __hip_bfloat16* __restrict__ wt,     // [NW+1][RP] normalized words
    const float* __restrict__ ent_emb,
    const float* __restrict__ rel_emb,
    const float* __restrict__ e_bias,
    const float* __restrict__ r_bias,
    const int* __restrict__ head,
    const int* __restrict__ relation,
    const int* __restrict__ tail,
    const int* __restrict__ head_w,
    const int* __restrict__ rel_w,
    const int* __restrict__ tail_w,
    const int* __restrict__ head_m,
    const int* __restrict__ rel_m,
    const int* __restrict__ tail_m,
    float* __restrict__ out,
    int B, int NW)
{
    int wid = (int)((blockIdx.x * (unsigned)blockDim.x + threadIdx.x) >> 6);
    int lane = (int)(threadIdx.x & 63u);
    if (wid >= B) return;
    int b = rfl(wid);                       // wave-uniform item index

    int d = lane;
    bool act = d < D;
    unsigned doff2 = (unsigned)((act ? d : 0) * 2);

    // ---- uniform index + bias loads (scalar pipe) ----
    int h = head[b];
    int r = relation[b];
    int t = tail[b];
    float bias = e_bias[h] + e_bias[t] + r_bias[r];

    // ---- issue entity row gathers early (coalesced, lane = dim) ----
    float fh = act ? ent_emb[(size_t)h * D + d] : 0.f;
    float fr = act ? rel_emb[(size_t)r * D + d] : 0.f;
    float ft = act ? ent_emb[(size_t)t * D + d] : 0.f;

    // ---- sanitize id lists in-register (uniform s_loads + scalar selects) ----
    const int* idp[3] = { head_w, rel_w, tail_w };
    const int* mkp[3] = { head_m, rel_m, tail_m };

    unsigned off[72];
    float cinv[3];
    #pragma unroll
    for (int s = 0; s < 3; ++s) {
        const int4* ip = (const int4*)(idp[s] + (size_t)b * L);   // uniform addr
        const int4* mp = (const int4*)(mkp[s] + (size_t)b * L);   // uniform addr
        int cnt = 0;
        #pragma unroll
        for (int i = 0; i < 6; ++i) {
            int4 ti = ip[i];
            int4 tm = mp[i];
            int s0 = tm.x ? ti.x : NW; cnt += (tm.x ? 1 : 0);
            int s1 = tm.y ? ti.y : NW; cnt += (tm.y ? 1 : 0);
            int s2 = tm.z ? ti.z : NW; cnt += (tm.z ? 1 : 0);
            int s3 = tm.w ? ti.w : NW; cnt += (tm.w ? 1 : 0);
            int base = s * 24 + 4 * i;
            off[base + 0] = ((unsigned)s0 << 7) + doff2;
            off[base + 1] = ((unsigned)s1 << 7) + doff2;
            off[base + 2] = ((unsigned)s2 << 7) + doff2;
            off[base + 3] = ((unsigned)s3 << 7) + doff2;
        }
        cinv[s] = 1.f / (float)(cnt > 0 ? cnt : 1);
    }

    // ---- issue all 72 word gathers flat ----
    const char* wtb = (const char*)wt;
    unsigned short raw[72];
    #pragma unroll
    for (int j = 0; j < 72; ++j)
        raw[j] = *(const unsigned short*)(wtb + off[j]);

    // ---- entity norms: 3 independent shfl chains (hidden under gathers) ----
    float ssh = wave_sum(fh * fh);
    float ssr = wave_sum(fr * fr);
    float sst = wave_sum(ft * ft);
    float vh = fh * (1.f / fmaxf(sqrtf(ssh), NORM_EPS));
    float vr = fr * (1.f / fmaxf(sqrtf(ssr), NORM_EPS));
    float vt = ft * (1.f / fmaxf(sqrtf(sst), NORM_EPS));

    // ---- pools ----
    float pool[3];
    #pragma unroll
    for (int s = 0; s < 3; ++s) {
        float s0 = 0.f, s1 = 0.f, s2 = 0.f, s3 = 0.f;
        #pragma unroll
        for (int l = 0; l < L; l += 4) {
            s0 += bf2f(raw[s * 24 + l + 0]);
            s1 += bf2f(raw[s * 24 + l + 1]);
            s2 += bf2f(raw[s * 24 + l + 2]);
            s3 += bf2f(raw[s * 24 + l + 3]);
        }
        pool[s] = ((s0 + s1) + (s2 + s3)) * cinv[s];
    }

    float comb = (vh + pool[0]) + (vr + pool[1]) - (vt + pool[2]);
    comb = act ? comb : 0.f;
    float nsc = sqrtf(wave_sum(comb * comb));

    float score = -nsc + bias;
    if (lane == 0) out[wid] = score;
}

// ---------- slow fallback (round-0 verified; used only if ws too small) ----------
__device__ __forceinline__ float word_pool_slow(const float* __restrict__ word_emb,
                                                const int* __restrict__ ids,
                                                const int* __restrict__ mask,
                                                int b, int d, bool act)
{
    float acc = 0.f;
    int cnt = 0;
    #pragma unroll
    for (int l = 0; l < L; ++l) {
        int m = mask[b * L + l];
        if (m) {
            int id = ids[b * L + l];
            float v = act ? word_emb[(size_t)id * D + d] : 0.f;
            float n = sqrtf(wave_sum(v * v));
            acc += v / fmaxf(n, NORM_EPS);
            cnt += 1;
        }
    }
    return acc / (float)(cnt > 0 ? cnt : 1);
}

__global__ __launch_bounds__(256) void transe_score_slow_kernel(
    const float* __restrict__ ent_emb, const float* __restrict__ rel_emb,
    const float* __restrict__ word_emb, const float* __restrict__ e_bias,
    const float* __restrict__ r_bias,
    const int* __restrict__ head, const int* __restrict__ relation,
    const int* __restrict__ tail,
    const int* __restrict__ head_w, const int* __restrict__ rel_w,
    const int* __restrict__ tail_w,
    const int* __restrict__ head_m, const int* __restrict__ rel_m,
    const int* __restrict__ tail_m,
    float* __restrict__ out, int B)
{
    int wid = (int)((blockIdx.x * (unsigned)blockDim.x + threadIdx.x) >> 6);
    int lane = (int)(threadIdx.x & 63u);
    if (wid >= B) return;
    int d = lane;
    bool act = d < D;

    int h = head[wid], r = relation[wid], t = tail[wid];

    float vh = act ? ent_emb[(size_t)h * D + d] : 0.f;
    float vr = act ? rel_emb[(size_t)r * D + d] : 0.f;
    float vt = act ? ent_emb[(size_t)t * D + d] : 0.f;
    vh /= fmaxf(sqrtf(wave_sum(vh * vh)), NORM_EPS);
    vr /= fmaxf(sqrtf(wave_sum(vr * vr)), NORM_EPS);
    vt /= fmaxf(sqrtf(wave_sum(vt * vt)), NORM_EPS);

    float ph = word_pool_slow(word_emb, head_w, head_m, wid, d, act);
    float pr = word_pool_slow(word_emb, rel_w,  rel_m,  wid, d, act);
    float pt = word_pool_slow(word_emb, tail_w, tail_m, wid, d, act);

    float comb = (vh + ph) + (vr + pr) - (vt + pt);
    float nsc = sqrtf(wave_sum(comb * comb));
    float score = -nsc + e_bias[h] + e_bias[t] + r_bias[r];
    if (lane == 0) out[wid] = score;
}

extern "C" void kernel_launch(void* const* d_in, const int* in_sizes, int n_in,
                              void* d_out, int out_size, void* d_ws, size_t ws_size,
                              hipStream_t stream) {
    const float* ent_emb  = (const float*)d_in[0];
    const float* rel_emb  = (const float*)d_in[1];
    const float* word_emb = (const float*)d_in[2];
    const float* e_bias   = (const float*)d_in[3];
    const float* r_bias   = (const float*)d_in[4];
    const int*   head     = (const int*)d_in[5];
    const int*   relation = (const int*)d_in[6];
    const int*   tail     = (const int*)d_in[7];
    const int*   head_w   = (const int*)d_in[8];
    const int*   rel_w    = (const int*)d_in[9];
    const int*   tail_w   = (const int*)d_in[10];
    const int*   head_m   = (const int*)d_in[11];
    const int*   rel_m    = (const int*)d_in[12];
    const int*   tail_m   = (const int*)d_in[13];
    float* out = (float*)d_out;

    int B  = in_sizes[5];
    int NW = in_sizes[2] / D;   // 100000

    int wpb = 256 / 64;  // waves per block

    size_t wt_bytes = (size_t)(NW + 1) * RP * sizeof(__hip_bfloat16);  // ~12.8 MB

    if (ws_size >= wt_bytes) {
        __hip_bfloat16* wt = (__hip_bfloat16*)d_ws;

        norm_bf16_tab_kernel<<<(NW + 1 + 255) / 256, 256, 0, stream>>>(word_emb, wt, NW);

        score_fused_kernel<<<(B + wpb - 1) / wpb, 256, 0, stream>>>(
            wt, ent_emb, rel_emb, e_bias, r_bias,
            head, relation, tail,
            head_w, rel_w, tail_w, head_m, rel_m, tail_m,
            out, B, NW);
    } else {
        transe_score_slow_kernel<<<(B + wpb - 1) / wpb, 256, 0, stream>>>(
            ent_emb, rel_emb, word_emb, e_bias, r_bias,
            head, relation, tail,
            head_w, rel_w, tail_w, head_m, rel_m, tail_m, out, B);
    }
}